// Round 3
// baseline (46.218 us; speedup 1.0000x reference)
//
#include <hip/hip_runtime.h>
#include <math.h>

#define B_ 16
#define N_ 288
#define C_ 32
#define H_ 32
#define BN_ (B_ * N_)     // 4608
#define NT 4              // nodes per wave in kernel 1
#define TI 6              // i-rows per block in kernel 2
#define NTILES (N_ / TI)  // 48

// ---------------------------------------------------------------------------
// ATTRIBUTION ROUND: kernels are byte-identical to round 2. K1 is launched 4x
// (idempotent) so dur_us = 4*K1 + K2; with round-2's K1 + K2 = 25.7us this
// solves the per-kernel split that rocprof's top-5 (all harness fills) hides.
// ---------------------------------------------------------------------------
__global__ __launch_bounds__(64) void gru_proj_kernel(
    const float* __restrict__ inputs, const float* __restrict__ states,
    const float* __restrict__ rzW,    const float* __restrict__ rzb,
    const float* __restrict__ hcW,    const float* __restrict__ hcb,
    const float* __restrict__ c1W,    const float* __restrict__ c1b,
    const float* __restrict__ c2W,    const float* __restrict__ c2b,
    float* __restrict__ out_state,
    float* __restrict__ ps1, float* __restrict__ pr1,
    float* __restrict__ ps2, float* __restrict__ pr2)
{
    const int lane  = threadIdx.x;     // 0..63
    const int o     = lane & 31;
    const int half  = lane >> 5;
    const int node0 = blockIdx.x * NT;

    __shared__ float rs_sh[NT][32];    // r * state      (broadcast source)
    __shared__ float a_sh[NT][32];     // relu(new_state)

    // ---- r_z = sigmoid(x @ rzW + rzb); lane = out unit (64) ----
    float acc[NT];
    const float rzbias = rzb[lane];
    #pragma unroll
    for (int t = 0; t < NT; ++t) acc[t] = rzbias;

    #pragma unroll
    for (int k = 0; k < C_; ++k) {
        const float wk = rzW[k * 64 + lane];
        #pragma unroll
        for (int t = 0; t < NT; ++t)
            acc[t] = fmaf(inputs[(node0 + t) * C_ + k], wk, acc[t]);
    }
    #pragma unroll
    for (int k = 0; k < H_; ++k) {
        const float wk = rzW[(C_ + k) * 64 + lane];
        #pragma unroll
        for (int t = 0; t < NT; ++t)
            acc[t] = fmaf(states[(node0 + t) * H_ + k], wk, acc[t]);
    }

    float z[NT], st[NT];
    #pragma unroll
    for (int t = 0; t < NT; ++t) {
        const float rzv = 1.0f / (1.0f + __expf(-acc[t]));
        const float r   = __shfl(rzv, o);
        z[t]  = __shfl(rzv, o + 32);
        st[t] = states[(node0 + t) * H_ + o];
        if (lane < 32) rs_sh[t][o] = r * st[t];
    }
    __syncthreads();

    // ---- h_cand = tanh(concat(x, r*state) @ hcW + hcb) ----
    float acc2[NT];
    #pragma unroll
    for (int t = 0; t < NT; ++t) acc2[t] = 0.0f;

    #pragma unroll
    for (int k = 0; k < C_; ++k) {
        const float wk = hcW[k * H_ + o];
        #pragma unroll
        for (int t = 0; t < NT; ++t)
            acc2[t] = fmaf(inputs[(node0 + t) * C_ + k], wk, acc2[t]);
    }
    #pragma unroll
    for (int q = 0; q < 8; ++q) {
        float4 rq[NT];
        #pragma unroll
        for (int t = 0; t < NT; ++t)
            rq[t] = *(const float4*)&rs_sh[t][q * 4];
        #pragma unroll
        for (int k4 = 0; k4 < 4; ++k4) {
            const float wk = hcW[(C_ + q * 4 + k4) * H_ + o];
            #pragma unroll
            for (int t = 0; t < NT; ++t)
                acc2[t] = fmaf(((const float*)&rq[t])[k4], wk, acc2[t]);
        }
    }

    const float hcbias = hcb[o];
    #pragma unroll
    for (int t = 0; t < NT; ++t) {
        const float e  = __expf(2.0f * (acc2[t] + hcbias));
        const float hc = 1.0f - 2.0f / (e + 1.0f);
        const float ns = z[t] * st[t] + (1.0f - z[t]) * hc;
        if (lane < 32) out_state[(node0 + t) * H_ + o] = ns;
        const float av = fmaxf(ns, 0.0f);
        if (lane < 32) a_sh[t][o] = av;
    }
    __syncthreads();

    // ---- projections ----
    const int rb = half * 32;
    float p1[NT], p2[NT];
    const float b1v = c1b[o], b2v = c2b[o];
    #pragma unroll
    for (int t = 0; t < NT; ++t) {
        p1[t] = half ? 0.0f : b1v;
        p2[t] = half ? 0.0f : b2v;
    }
    #pragma unroll
    for (int q = 0; q < 8; ++q) {
        float4 aq[NT];
        #pragma unroll
        for (int t = 0; t < NT; ++t)
            aq[t] = *(const float4*)&a_sh[t][q * 4];
        #pragma unroll
        for (int k4 = 0; k4 < 4; ++k4) {
            const int h    = q * 4 + k4;
            const float w1 = c1W[(rb + h) * H_ + o];
            const float w2 = c2W[(rb + h) * H_ + o];
            #pragma unroll
            for (int t = 0; t < NT; ++t) {
                const float av = ((const float*)&aq[t])[k4];
                p1[t] = fmaf(av, w1, p1[t]);
                p2[t] = fmaf(av, w2, p2[t]);
            }
        }
    }
    float* d1 = half ? pr1 : ps1;
    float* d2 = half ? pr2 : ps2;
    #pragma unroll
    for (int t = 0; t < NT; ++t) {
        d1[(node0 + t) * H_ + o] = p1[t];
        d2[(node0 + t) * H_ + o] = p2[t];
    }
}

__global__ __launch_bounds__(320) void pair_kernel(
    const float* __restrict__ ps1, const float* __restrict__ pr1,
    const float* __restrict__ ps2, const float* __restrict__ pr2,
    const float* __restrict__ w1g, const float* __restrict__ b1g,
    const float* __restrict__ w2g, const float* __restrict__ b2g,
    float* __restrict__ out)
{
    const int j  = threadIdx.x;
    const int b  = blockIdx.x / NTILES;
    const int i0 = (blockIdx.x % NTILES) * TI;
    if (j >= N_) return;

    const size_t rowbase = (size_t)(b * N_ + i0) * H_;
    float acc1[TI];
    float4 p[8];
    float  wv[32];

    // ---- conv1 (support) ----
    {
        const float4* prp = (const float4*)(pr1 + (size_t)(b * N_ + j) * H_);
        #pragma unroll
        for (int c = 0; c < 8; ++c) p[c] = prp[c];
        #pragma unroll
        for (int h = 0; h < 32; ++h) wv[h] = w1g[h];
        const float b1 = b1g[0];
        #pragma unroll
        for (int ii = 0; ii < TI; ++ii) {
            const float4* sp = (const float4*)(ps1 + rowbase + (size_t)ii * H_);
            float aA = b1, aB = 0.0f;
            #pragma unroll
            for (int c = 0; c < 8; ++c) {
                const float4 sv = sp[c];
                const float t0 = fmaxf(sv.x + p[c].x, 0.0f);
                const float t1 = fmaxf(sv.y + p[c].y, 0.0f);
                const float t2 = fmaxf(sv.z + p[c].z, 0.0f);
                const float t3 = fmaxf(sv.w + p[c].w, 0.0f);
                aA = fmaf(t0, wv[4 * c + 0], aA);
                aB = fmaf(t1, wv[4 * c + 1], aB);
                aA = fmaf(t2, wv[4 * c + 2], aA);
                aB = fmaf(t3, wv[4 * c + 3], aB);
            }
            acc1[ii] = aA + aB;
        }
    }

    // ---- conv2 (mask) + epilogue ----
    {
        const float4* prp = (const float4*)(pr2 + (size_t)(b * N_ + j) * H_);
        #pragma unroll
        for (int c = 0; c < 8; ++c) p[c] = prp[c];
        #pragma unroll
        for (int h = 0; h < 32; ++h) wv[h] = w2g[h];
        const float b2 = b2g[0];
        float* orow = out + (size_t)(b * N_ + i0) * N_ + j;
        #pragma unroll
        for (int ii = 0; ii < TI; ++ii) {
            const float4* sp = (const float4*)(ps2 + rowbase + (size_t)ii * H_);
            float aA = b2, aB = 0.0f;
            #pragma unroll
            for (int c = 0; c < 8; ++c) {
                const float4 sv = sp[c];
                const float t0 = fmaxf(sv.x + p[c].x, 0.0f);
                const float t1 = fmaxf(sv.y + p[c].y, 0.0f);
                const float t2 = fmaxf(sv.z + p[c].z, 0.0f);
                const float t3 = fmaxf(sv.w + p[c].w, 0.0f);
                aA = fmaf(t0, wv[4 * c + 0], aA);
                aB = fmaf(t1, wv[4 * c + 1], aB);
                aA = fmaf(t2, wv[4 * c + 2], aA);
                aB = fmaf(t3, wv[4 * c + 3], aB);
            }
            const float m   = aA + aB;
            const float sig = 1.0f / (1.0f + __expf(-m));
            orow[(size_t)ii * N_] = acc1[ii] * sig;
        }
    }
}

extern "C" void kernel_launch(void* const* d_in, const int* in_sizes, int n_in,
                              void* d_out, int out_size, void* d_ws, size_t ws_size,
                              hipStream_t stream) {
    const float* inputs = (const float*)d_in[0];
    const float* states = (const float*)d_in[1];
    const float* rzW    = (const float*)d_in[2];
    const float* rzb    = (const float*)d_in[3];
    const float* hcW    = (const float*)d_in[4];
    const float* hcb    = (const float*)d_in[5];
    const float* c1W    = (const float*)d_in[6];
    const float* c1b    = (const float*)d_in[7];
    const float* c1w1   = (const float*)d_in[8];
    const float* c1b1   = (const float*)d_in[9];
    const float* c2W    = (const float*)d_in[10];
    const float* c2b    = (const float*)d_in[11];
    const float* c2w1   = (const float*)d_in[12];
    const float* c2b1   = (const float*)d_in[13];

    float* out_support = (float*)d_out;
    float* out_state   = out_support + (size_t)BN_ * N_;

    float* ws  = (float*)d_ws;
    float* ps1 = ws;
    float* pr1 = ws + 1 * (size_t)BN_ * H_;
    float* ps2 = ws + 2 * (size_t)BN_ * H_;
    float* pr2 = ws + 3 * (size_t)BN_ * H_;

    // Attribution probe: K1 x4 (idempotent), K2 x1.
    // dur_us = 4*K1 + K2 ; round-2 dur (K1+K2) = 25.7us -> K1 = (dur-25.7)/3.
    for (int rep = 0; rep < 4; ++rep) {
        gru_proj_kernel<<<BN_ / NT, 64, 0, stream>>>(
            inputs, states, rzW, rzb, hcW, hcb, c1W, c1b, c2W, c2b,
            out_state, ps1, pr1, ps2, pr2);
    }

    pair_kernel<<<B_ * NTILES, 320, 0, stream>>>(
        ps1, pr1, ps2, pr2, c1w1, c1b1, c2w1, c2b1, out_support);
}

// Round 4
// 33.844 us; speedup vs baseline: 1.3656x; 1.3656x over previous
//
#include <hip/hip_runtime.h>
#include <math.h>

#define B_ 16
#define N_ 288
#define C_ 32
#define H_ 32
#define BN_ (B_ * N_)     // 4608

#define K1_WAVES 4
#define K1_NT 2                       // nodes per wave
#define K1_NODES (K1_WAVES * K1_NT)   // 8 nodes per block

#define TI 4              // i-rows per block in kernel 2
#define NTILES (N_ / TI)  // 72

// ---------------------------------------------------------------------------
// Kernel 1: GRU cell + sender/receiver projections. 4 waves/block (share
// weight loads through L1), NT=2 nodes/wave -> 576 blocks, 2304 waves
// (2.25/SIMD vs 1.1 before). Wave-private LDS regions, NO barriers (in-wave
// DS ordering is program-order). fc2 bias folded into sender projection.
// ---------------------------------------------------------------------------
__global__ __launch_bounds__(256) void gru_proj_kernel(
    const float* __restrict__ inputs, const float* __restrict__ states,
    const float* __restrict__ rzW,    const float* __restrict__ rzb,
    const float* __restrict__ hcW,    const float* __restrict__ hcb,
    const float* __restrict__ c1W,    const float* __restrict__ c1b,
    const float* __restrict__ c2W,    const float* __restrict__ c2b,
    float* __restrict__ out_state,
    float* __restrict__ ps1, float* __restrict__ pr1,
    float* __restrict__ ps2, float* __restrict__ pr2)
{
    const int tid   = threadIdx.x;
    const int w     = tid >> 6;
    const int lane  = tid & 63;
    const int o     = lane & 31;
    const int half  = lane >> 5;
    const int node0 = blockIdx.x * K1_NODES + w * K1_NT;

    __shared__ __align__(16) float rs_sh[K1_WAVES][K1_NT][32]; // r * state
    __shared__ __align__(16) float a_sh[K1_WAVES][K1_NT][32];  // relu(ns)

    // ---- r_z = sigmoid(x @ rzW + rzb); lane = out unit (64) ----
    float acc[K1_NT];
    const float rzbias = rzb[lane];
    #pragma unroll
    for (int t = 0; t < K1_NT; ++t) acc[t] = rzbias;

    #pragma unroll
    for (int k = 0; k < C_; ++k) {
        const float wk = rzW[k * 64 + lane];
        #pragma unroll
        for (int t = 0; t < K1_NT; ++t)
            acc[t] = fmaf(inputs[(node0 + t) * C_ + k], wk, acc[t]);
    }
    #pragma unroll
    for (int k = 0; k < H_; ++k) {
        const float wk = rzW[(C_ + k) * 64 + lane];
        #pragma unroll
        for (int t = 0; t < K1_NT; ++t)
            acc[t] = fmaf(states[(node0 + t) * H_ + k], wk, acc[t]);
    }

    float z[K1_NT], st[K1_NT];
    #pragma unroll
    for (int t = 0; t < K1_NT; ++t) {
        const float rzv = 1.0f / (1.0f + __expf(-acc[t]));
        const float r   = __shfl(rzv, o);        // r[o] to both halves
        z[t]  = __shfl(rzv, o + 32);             // z[o] to both halves
        st[t] = states[(node0 + t) * H_ + o];
        if (lane < 32) rs_sh[w][t][o] = r * st[t];
    }

    // ---- h_cand = tanh(concat(x, r*state) @ hcW + hcb) ----
    float acc2[K1_NT];
    #pragma unroll
    for (int t = 0; t < K1_NT; ++t) acc2[t] = 0.0f;

    #pragma unroll
    for (int k = 0; k < C_; ++k) {
        const float wk = hcW[k * H_ + o];
        #pragma unroll
        for (int t = 0; t < K1_NT; ++t)
            acc2[t] = fmaf(inputs[(node0 + t) * C_ + k], wk, acc2[t]);
    }
    #pragma unroll
    for (int q = 0; q < 8; ++q) {                 // k = 32..63 via LDS quads
        float4 rq[K1_NT];
        #pragma unroll
        for (int t = 0; t < K1_NT; ++t)
            rq[t] = *(const float4*)&rs_sh[w][t][q * 4];
        #pragma unroll
        for (int k4 = 0; k4 < 4; ++k4) {
            const float wk = hcW[(C_ + q * 4 + k4) * H_ + o];
            #pragma unroll
            for (int t = 0; t < K1_NT; ++t)
                acc2[t] = fmaf(((const float*)&rq[t])[k4], wk, acc2[t]);
        }
    }

    const float hcbias = hcb[o];
    #pragma unroll
    for (int t = 0; t < K1_NT; ++t) {
        // tanh(x) = 1 - 2/(exp(2x)+1)
        const float e  = __expf(2.0f * (acc2[t] + hcbias));
        const float hc = 1.0f - 2.0f / (e + 1.0f);
        const float ns = z[t] * st[t] + (1.0f - z[t]) * hc;
        if (lane < 32) out_state[(node0 + t) * H_ + o] = ns;
        const float av = fmaxf(ns, 0.0f);
        if (lane < 32) a_sh[w][t][o] = av;
    }

    // ---- projections: lane = [sender unit o | receiver unit o] ----
    const int rb = half * 32;
    float p1[K1_NT], p2[K1_NT];
    const float b1v = c1b[o], b2v = c2b[o];
    #pragma unroll
    for (int t = 0; t < K1_NT; ++t) {
        p1[t] = half ? 0.0f : b1v;                // fc2 bias folded into sender
        p2[t] = half ? 0.0f : b2v;
    }
    #pragma unroll
    for (int q = 0; q < 8; ++q) {
        float4 aq[K1_NT];
        #pragma unroll
        for (int t = 0; t < K1_NT; ++t)
            aq[t] = *(const float4*)&a_sh[w][t][q * 4];
        #pragma unroll
        for (int k4 = 0; k4 < 4; ++k4) {
            const int h    = q * 4 + k4;
            const float w1 = c1W[(rb + h) * H_ + o];
            const float w2 = c2W[(rb + h) * H_ + o];
            #pragma unroll
            for (int t = 0; t < K1_NT; ++t) {
                const float av = ((const float*)&aq[t])[k4];
                p1[t] = fmaf(av, w1, p1[t]);
                p2[t] = fmaf(av, w2, p2[t]);
            }
        }
    }
    float* d1 = half ? pr1 : ps1;
    float* d2 = half ? pr2 : ps2;
    #pragma unroll
    for (int t = 0; t < K1_NT; ++t) {
        d1[(node0 + t) * H_ + o] = p1[t];
        d2[(node0 + t) * H_ + o] = p2[t];
    }
}

// ---------------------------------------------------------------------------
// Kernel 2: pair conv. Block = (batch b, TI=4 sender rows), thread = column j.
// Sender rows staged in LDS (one coalesced load + barrier), inner loop is
// pure ds_read_b128 broadcast + VALU -- no SMEM lgkmcnt(0) drains. pr[j] in
// VGPRs, fc1 weights uniform -> SGPRs. 1152 blocks -> ~5.6 waves/SIMD.
// ---------------------------------------------------------------------------
__global__ __launch_bounds__(320) void pair_kernel(
    const float* __restrict__ ps1, const float* __restrict__ pr1,
    const float* __restrict__ ps2, const float* __restrict__ pr2,
    const float* __restrict__ w1g, const float* __restrict__ b1g,
    const float* __restrict__ w2g, const float* __restrict__ b2g,
    float* __restrict__ out)
{
    const int tid = threadIdx.x;
    const int b   = blockIdx.x / NTILES;
    const int i0  = (blockIdx.x % NTILES) * TI;
    const int j   = tid;

    __shared__ __align__(16) float s1[TI * 32];
    __shared__ __align__(16) float s2[TI * 32];

    const size_t rowbase = (size_t)(b * N_ + i0) * H_;
    if (tid < TI * 32)            s1[tid]            = ps1[rowbase + tid];
    else if (tid < 2 * TI * 32)   s2[tid - TI * 32]  = ps2[rowbase + (tid - TI * 32)];
    __syncthreads();

    if (j < N_) {
        float acc1[TI];
        float4 p[8];
        float  wv[32];

        // ---- conv1 (support) ----
        {
            const float4* prp = (const float4*)(pr1 + (size_t)(b * N_ + j) * H_);
            #pragma unroll
            for (int c = 0; c < 8; ++c) p[c] = prp[c];
            #pragma unroll
            for (int h = 0; h < 32; ++h) wv[h] = w1g[h];   // uniform -> SGPR
            const float b1 = b1g[0];
            #pragma unroll
            for (int ii = 0; ii < TI; ++ii) {
                const float4* sp = (const float4*)&s1[ii * 32];
                float aA = b1, aB = 0.0f;
                #pragma unroll
                for (int c = 0; c < 8; ++c) {
                    const float4 sv = sp[c];               // ds_read broadcast
                    const float t0 = fmaxf(sv.x + p[c].x, 0.0f);
                    const float t1 = fmaxf(sv.y + p[c].y, 0.0f);
                    const float t2 = fmaxf(sv.z + p[c].z, 0.0f);
                    const float t3 = fmaxf(sv.w + p[c].w, 0.0f);
                    aA = fmaf(t0, wv[4 * c + 0], aA);
                    aB = fmaf(t1, wv[4 * c + 1], aB);
                    aA = fmaf(t2, wv[4 * c + 2], aA);
                    aB = fmaf(t3, wv[4 * c + 3], aB);
                }
                acc1[ii] = aA + aB;
            }
        }

        // ---- conv2 (mask) + epilogue ----
        {
            const float4* prp = (const float4*)(pr2 + (size_t)(b * N_ + j) * H_);
            #pragma unroll
            for (int c = 0; c < 8; ++c) p[c] = prp[c];
            #pragma unroll
            for (int h = 0; h < 32; ++h) wv[h] = w2g[h];
            const float b2 = b2g[0];
            float* orow = out + (size_t)(b * N_ + i0) * N_ + j;
            #pragma unroll
            for (int ii = 0; ii < TI; ++ii) {
                const float4* sp = (const float4*)&s2[ii * 32];
                float aA = b2, aB = 0.0f;
                #pragma unroll
                for (int c = 0; c < 8; ++c) {
                    const float4 sv = sp[c];
                    const float t0 = fmaxf(sv.x + p[c].x, 0.0f);
                    const float t1 = fmaxf(sv.y + p[c].y, 0.0f);
                    const float t2 = fmaxf(sv.z + p[c].z, 0.0f);
                    const float t3 = fmaxf(sv.w + p[c].w, 0.0f);
                    aA = fmaf(t0, wv[4 * c + 0], aA);
                    aB = fmaf(t1, wv[4 * c + 1], aB);
                    aA = fmaf(t2, wv[4 * c + 2], aA);
                    aB = fmaf(t3, wv[4 * c + 3], aB);
                }
                const float m   = aA + aB;
                const float sig = 1.0f / (1.0f + __expf(-m));
                orow[(size_t)ii * N_] = acc1[ii] * sig;
            }
        }
    }
}

extern "C" void kernel_launch(void* const* d_in, const int* in_sizes, int n_in,
                              void* d_out, int out_size, void* d_ws, size_t ws_size,
                              hipStream_t stream) {
    const float* inputs = (const float*)d_in[0];
    const float* states = (const float*)d_in[1];
    const float* rzW    = (const float*)d_in[2];
    const float* rzb    = (const float*)d_in[3];
    const float* hcW    = (const float*)d_in[4];
    const float* hcb    = (const float*)d_in[5];
    const float* c1W    = (const float*)d_in[6];
    const float* c1b    = (const float*)d_in[7];
    const float* c1w1   = (const float*)d_in[8];
    const float* c1b1   = (const float*)d_in[9];
    const float* c2W    = (const float*)d_in[10];
    const float* c2b    = (const float*)d_in[11];
    const float* c2w1   = (const float*)d_in[12];
    const float* c2b1   = (const float*)d_in[13];

    float* out_support = (float*)d_out;
    float* out_state   = out_support + (size_t)BN_ * N_;

    float* ws  = (float*)d_ws;
    float* ps1 = ws;
    float* pr1 = ws + 1 * (size_t)BN_ * H_;
    float* ps2 = ws + 2 * (size_t)BN_ * H_;
    float* pr2 = ws + 3 * (size_t)BN_ * H_;

    gru_proj_kernel<<<BN_ / K1_NODES, 256, 0, stream>>>(
        inputs, states, rzW, rzb, hcW, hcb, c1W, c1b, c2W, c2b,
        out_state, ps1, pr1, ps2, pr2);

    pair_kernel<<<B_ * NTILES, 320, 0, stream>>>(
        ps1, pr1, ps2, pr2, c1w1, c1b1, c2w1, c2b1, out_support);
}